// Round 3
// baseline (83.099 us; speedup 1.0000x reference)
//
#include <hip/hip_runtime.h>

#define IN_FLAT 1024
#define BATCH   512
#define NEURONS 4096
#define FOCUS   64
#define BT      8
// per-chunk x^T block: [2 planes][1024 features][4 batches] f32 = 32 KB
#define CHUNK_FLOATS (IN_FLAT * BT)          // 8192
#define PLANE_FLOATS (IN_FLAT * 4)           // 4096
#define PLANE_BYTES  (PLANE_FLOATS * 4)      // 16384

// ---------- kernel 1: transpose f32 ----------
// x [BATCH][IN_FLAT] -> xt chunks: chunk c (batches c*8..c*8+7), feature i,
// float index = c*8192 + (b&4 ? 4096 : 0) + i*4 + (b&3)
__global__ __launch_bounds__(256) void transpose_f32_kernel(
        const float* __restrict__ x, float* __restrict__ xt) {
    __shared__ float tile[32][33];
    const int i0 = blockIdx.x * 32;   // feature tile
    const int b0 = blockIdx.y * 32;   // batch tile
    const int t  = threadIdx.x;

    {   // coalesced read: 32 batch rows x 32 features
        const int r  = t >> 3;
        const int c4 = t & 7;
        float4 v = *reinterpret_cast<const float4*>(
            x + (size_t)(b0 + r) * IN_FLAT + i0 + c4 * 4);
        tile[r][c4 * 4 + 0] = v.x;
        tile[r][c4 * 4 + 1] = v.y;
        tile[r][c4 * 4 + 2] = v.z;
        tile[r][c4 * 4 + 3] = v.w;
    }
    __syncthreads();

    {   // write: 4 consecutive batches of one feature -> one float4
        const int il = t >> 3;        // feature within tile
        const int q  = t & 7;         // batches q*4 .. q*4+3
        float4 o;
        o.x = tile[q * 4 + 0][il];
        o.y = tile[q * 4 + 1][il];
        o.z = tile[q * 4 + 2][il];
        o.w = tile[q * 4 + 3][il];
        const int chunk = (b0 >> 3) + (q >> 1);
        const int plane = q & 1;
        float* dst = xt + (size_t)chunk * CHUNK_FLOATS + plane * PLANE_FLOATS
                        + (size_t)(i0 + il) * 4;
        *reinterpret_cast<float4*>(dst) = o;   // 16B aligned
    }
}

// ---------- kernel 2: pack idx+w ----------
// pw[tile][f>>1][n_local][f&1] = { (idx & 1023) * 16 (LDS byte off), w bits }
// so main loop reads uint4 = two (off,w) pairs, coalesced across lanes.
__global__ __launch_bounds__(256) void pack_pw_kernel(
        const int* __restrict__ idx, const float* __restrict__ w,
        uint2* __restrict__ pw) {
    const int tid = blockIdx.x * 256 + threadIdx.x;   // 0..262143
    const int n = tid >> 6;
    const int f = tid & 63;
    const int i = idx[tid] & (IN_FLAT - 1);
    uint2 e;
    e.x = (unsigned)(i * 16);
    e.y = __float_as_uint(w[tid]);
    const int dst = ((n >> 8) * 32 + (f >> 1)) * 512 + (n & 255) * 2 + (f & 1);
    pw[dst] = e;
}

// ---------- kernel 3: gather-dot ----------
// block = 256 neurons x 8 batches. LDS = 32KB f32 x^T chunk, split planes.
// Per f: one coalesced uint4 pw load covers 2 f; per f two ds_read_b128
// (plane0 at off, plane1 at off+16384), then 8 pure FMAs. No unpack, no
// address VALU (offset is precomputed).
__global__ __launch_bounds__(256) void gather_dot_kernel(
        const float* __restrict__ xt,
        const uint4* __restrict__ pw4,
        const float* __restrict__ bias,
        float*       __restrict__ y) {
    __shared__ float lx[CHUNK_FLOATS];   // 32 KB

    const int nb = blockIdx.x;    // 0..15 neuron tile
    const int bb = blockIdx.y;    // 0..63 batch chunk
    const int t  = threadIdx.x;

    {   // stage 32 KB contiguously
        const uint4* src = reinterpret_cast<const uint4*>(
            xt + (size_t)bb * CHUNK_FLOATS);
        uint4* dst = reinterpret_cast<uint4*>(lx);
        #pragma unroll
        for (int u = 0; u < 8; ++u)
            dst[u * 256 + t] = src[u * 256 + t];
    }
    __syncthreads();

    float acc[BT];
    #pragma unroll
    for (int k = 0; k < BT; ++k) acc[k] = 0.f;

    const uint4* pt = pw4 + (size_t)nb * 8192;   // nb*32*256
    const char*  lxb = reinterpret_cast<const char*>(lx);

    #pragma unroll 4
    for (int f2 = 0; f2 < 32; ++f2) {
        const uint4 p = pt[f2 * 256 + t];
        const float4 a0 = *reinterpret_cast<const float4*>(lxb + p.x);
        const float4 b0 = *reinterpret_cast<const float4*>(lxb + p.x + PLANE_BYTES);
        const float4 a1 = *reinterpret_cast<const float4*>(lxb + p.z);
        const float4 b1 = *reinterpret_cast<const float4*>(lxb + p.z + PLANE_BYTES);
        const float w0 = __uint_as_float(p.y);
        const float w1 = __uint_as_float(p.w);
        acc[0] += w0 * a0.x;  acc[1] += w0 * a0.y;
        acc[2] += w0 * a0.z;  acc[3] += w0 * a0.w;
        acc[4] += w0 * b0.x;  acc[5] += w0 * b0.y;
        acc[6] += w0 * b0.z;  acc[7] += w0 * b0.w;
        acc[0] += w1 * a1.x;  acc[1] += w1 * a1.y;
        acc[2] += w1 * a1.z;  acc[3] += w1 * a1.w;
        acc[4] += w1 * b1.x;  acc[5] += w1 * b1.y;
        acc[6] += w1 * b1.z;  acc[7] += w1 * b1.w;
    }

    const int n  = nb * 256 + t;
    const float bv = bias[n];
    const int b0 = bb * BT;
    #pragma unroll
    for (int k = 0; k < BT; ++k) {
        y[(size_t)(b0 + k) * NEURONS + n] = acc[k] + bv;   // coalesced over n
    }
}

// ---------- launch ----------
extern "C" void kernel_launch(void* const* d_in, const int* in_sizes, int n_in,
                              void* d_out, int out_size, void* d_ws, size_t ws_size,
                              hipStream_t stream) {
    const float* x    = (const float*)d_in[0];
    const int*   idx  = (const int*)  d_in[1];
    const float* w    = (const float*)d_in[2];
    const float* bias = (const float*)d_in[3];
    float*       y    = (float*)d_out;

    // ws layout: xt f32 (2 MB) | pw uint2 (2 MB)
    float* xt = (float*)d_ws;
    uint2* pw = (uint2*)((char*)d_ws + (size_t)BATCH * IN_FLAT * 4);

    transpose_f32_kernel<<<dim3(IN_FLAT / 32, BATCH / 32), 256, 0, stream>>>(x, xt);
    pack_pw_kernel<<<dim3(NEURONS * FOCUS / 256), 256, 0, stream>>>(idx, w, pw);
    gather_dot_kernel<<<dim3(NEURONS / 256, BATCH / BT), 256, 0, stream>>>(
        xt, (const uint4*)pw, bias, y);
}

// Round 4
// 82.221 us; speedup vs baseline: 1.0107x; 1.0107x over previous
//
#include <hip/hip_runtime.h>

#define IN_FLAT 1024
#define BATCH   512
#define NEURONS 4096
#define FOCUS   64

typedef __bf16 bf16x8 __attribute__((ext_vector_type(8)));
typedef float  f32x4  __attribute__((ext_vector_type(4)));

// ---------- helpers ----------
__device__ __forceinline__ unsigned short f32_to_bf16(float f) {
    unsigned int u = __float_as_uint(f);
    unsigned int r = (u + 0x7fffu + ((u >> 16) & 1u)) >> 16;  // RNE
    return (unsigned short)r;
}
__device__ __forceinline__ unsigned int pack2(float a, float b) {
    return (unsigned int)f32_to_bf16(a) | ((unsigned int)f32_to_bf16(b) << 16);
}

// ---------- kernel 1: scatter weights into dense W^T (bf16) ----------
// Wt[n][i] = sum over f with idx[n,f]==i of w[n,f].  Block = 8 neuron rows,
// accumulated in LDS f32 (handles duplicate indices), then converted to bf16.
__global__ __launch_bounds__(256) void build_wt_kernel(
        const int* __restrict__ idx, const float* __restrict__ w,
        unsigned short* __restrict__ Wt) {
    __shared__ float rb[8 * IN_FLAT];          // 32 KB
    const int t  = threadIdx.x;
    const int g0 = blockIdx.x * 8;             // first neuron of this block

    float4* rb4 = reinterpret_cast<float4*>(rb);
    #pragma unroll
    for (int u = 0; u < 8; ++u)
        rb4[u * 256 + t] = float4{0.f, 0.f, 0.f, 0.f};
    __syncthreads();

    const int base = g0 * FOCUS;               // 512 (idx,w) pairs, contiguous
    #pragma unroll
    for (int p = t; p < 8 * FOCUS; p += 256) {
        const int   i  = idx[base + p] & (IN_FLAT - 1);
        const float ww = w[base + p];
        atomicAdd(&rb[(p >> 6) * IN_FLAT + i], ww);   // LDS ds_add_f32
    }
    __syncthreads();

    uint4* dst = reinterpret_cast<uint4*>(Wt + (size_t)g0 * IN_FLAT);
    #pragma unroll
    for (int c = 0; c < 4; ++c) {              // 8 rows * 1024 = 8192 elems
        const float4 lo = rb4[c * 512 + t * 2];
        const float4 hi = rb4[c * 512 + t * 2 + 1];
        dst[c * 256 + t] = uint4{pack2(lo.x, lo.y), pack2(lo.z, lo.w),
                                 pack2(hi.x, hi.y), pack2(hi.z, hi.w)};
    }
}

// ---------- kernel 2: convert x f32 -> bf16 (row-major unchanged) ----------
__global__ __launch_bounds__(256) void convert_x_kernel(
        const float* __restrict__ x, unsigned short* __restrict__ A) {
    const int t = blockIdx.x * 256 + threadIdx.x;   // 65536 threads * 8 elems
    const float4 lo = reinterpret_cast<const float4*>(x)[t * 2];
    const float4 hi = reinterpret_cast<const float4*>(x)[t * 2 + 1];
    reinterpret_cast<uint4*>(A)[t] = uint4{pack2(lo.x, lo.y), pack2(lo.z, lo.w),
                                           pack2(hi.x, hi.y), pack2(hi.z, hi.w)};
}

// ---------- kernel 3: GEMM  y[b][n] = sum_k A[b][k]*Wt[n][k] + bias[n] ----------
// 64x64 block tile, BK=64, 4 waves (each 32x32), double-buffered LDS,
// XOR-swizzled tiles (byte ^= (row&7)<<4) -> conflict-free ds_read_b128.
__global__ __launch_bounds__(256) void gemm_kernel(
        const unsigned short* __restrict__ A,
        const unsigned short* __restrict__ W,
        const float* __restrict__ bias,
        float* __restrict__ y) {
    __shared__ uint4 smem4[2048];              // 32 KB = 2 x (A 8KB | B 8KB)
    char* smem = reinterpret_cast<char*>(smem4);

    // XCD-aware swizzle: each XCD gets an 8(M) x 8(N) sub-grid (512 % 8 == 0)
    const int b   = blockIdx.x;
    const int xcd = b & 7, jj = b >> 3;
    const int m0  = (jj & 7) * 64;
    const int n0  = (xcd * 8 + (jj >> 3)) * 64;

    const int tid  = threadIdx.x;
    const int lane = tid & 63;
    const int wv   = tid >> 6;
    const int wr   = wv >> 1, wc = wv & 1;     // wave tile: rows wr*32, cols wc*32

    // staging: thread owns logical 16B slots s0=tid*16 (rows 0..31) and s1=s0+4096
    const int s0 = tid * 16, s1 = s0 + 4096;
    const int r0 = s0 >> 7,  r1 = s1 >> 7;
    const int c0 = (s0 & 127) >> 1, c1 = (s1 & 127) >> 1;   // k-elem offset
    const unsigned short* gA0 = A + (m0 + r0) * IN_FLAT + c0;
    const unsigned short* gA1 = A + (m0 + r1) * IN_FLAT + c1;
    const unsigned short* gB0 = W + (size_t)(n0 + r0) * IN_FLAT + c0;
    const unsigned short* gB1 = W + (size_t)(n0 + r1) * IN_FLAT + c1;
    const int dA0 = s0 ^ ((r0 & 7) << 4);
    const int dA1 = s1 ^ ((r1 & 7) << 4);
    const int dB0 = dA0 + 8192, dB1 = dA1 + 8192;

    f32x4 acc[2][2] = {};
    uint4 ra0, ra1, rb0, rb1;

    ra0 = *reinterpret_cast<const uint4*>(gA0);
    ra1 = *reinterpret_cast<const uint4*>(gA1);
    rb0 = *reinterpret_cast<const uint4*>(gB0);
    rb1 = *reinterpret_cast<const uint4*>(gB1);

    for (int t = 0; t < IN_FLAT / 64; ++t) {   // 16 K-tiles
        const int bb = (t & 1) << 14;
        *reinterpret_cast<uint4*>(smem + bb + dA0) = ra0;
        *reinterpret_cast<uint4*>(smem + bb + dA1) = ra1;
        *reinterpret_cast<uint4*>(smem + bb + dB0) = rb0;
        *reinterpret_cast<uint4*>(smem + bb + dB1) = rb1;
        __syncthreads();

        if (t < 15) {                          // prefetch next tile into regs
            const int k = (t + 1) * 64;
            ra0 = *reinterpret_cast<const uint4*>(gA0 + k);
            ra1 = *reinterpret_cast<const uint4*>(gA1 + k);
            rb0 = *reinterpret_cast<const uint4*>(gB0 + k);
            rb1 = *reinterpret_cast<const uint4*>(gB1 + k);
        }

        #pragma unroll
        for (int ks = 0; ks < 2; ++ks) {
            const int kb = ks * 64 + ((lane >> 4) << 4);   // byte offset in row
            bf16x8 af[2], bfr[2];
            #pragma unroll
            for (int fm = 0; fm < 2; ++fm) {
                const int row = wr * 32 + fm * 16 + (lane & 15);
                const int L   = row * 128 + kb;
                af[fm] = *reinterpret_cast<const bf16x8*>(
                    smem + bb + (L ^ ((row & 7) << 4)));
            }
            #pragma unroll
            for (int fn = 0; fn < 2; ++fn) {
                const int row = wc * 32 + fn * 16 + (lane & 15);
                const int L   = row * 128 + kb;
                bfr[fn] = *reinterpret_cast<const bf16x8*>(
                    smem + bb + 8192 + (L ^ ((row & 7) << 4)));
            }
            #pragma unroll
            for (int fm = 0; fm < 2; ++fm)
                #pragma unroll
                for (int fn = 0; fn < 2; ++fn)
                    acc[fm][fn] = __builtin_amdgcn_mfma_f32_16x16x32_bf16(
                        af[fm], bfr[fn], acc[fm][fn], 0, 0, 0);
        }
        __syncthreads();   // before next iter's ds_write overwrites other buffer users
    }

    // epilogue: C/D layout col=lane&15, row=(lane>>4)*4+reg
    const int nbase = n0 + wc * 32 + (lane & 15);
    const int mbase = m0 + wr * 32 + ((lane >> 4) << 2);
    #pragma unroll
    for (int fn = 0; fn < 2; ++fn) {
        const float bv = bias[nbase + fn * 16];
        #pragma unroll
        for (int fm = 0; fm < 2; ++fm) {
            #pragma unroll
            for (int jr = 0; jr < 4; ++jr) {
                y[(size_t)(mbase + fm * 16 + jr) * NEURONS + nbase + fn * 16] =
                    acc[fm][fn][jr] + bv;
            }
        }
    }
}

// ---------- launch ----------
extern "C" void kernel_launch(void* const* d_in, const int* in_sizes, int n_in,
                              void* d_out, int out_size, void* d_ws, size_t ws_size,
                              hipStream_t stream) {
    const float* x    = (const float*)d_in[0];
    const int*   idx  = (const int*)  d_in[1];
    const float* w    = (const float*)d_in[2];
    const float* bias = (const float*)d_in[3];
    float*       y    = (float*)d_out;

    // ws: Wt bf16 [4096][1024] (8 MB) | A bf16 [512][1024] (1 MB)
    unsigned short* Wt = (unsigned short*)d_ws;
    unsigned short* A  = (unsigned short*)((char*)d_ws + (size_t)NEURONS * IN_FLAT * 2);

    build_wt_kernel<<<NEURONS / 8, 256, 0, stream>>>(idx, w, Wt);
    convert_x_kernel<<<BATCH * IN_FLAT / (256 * 8), 256, 0, stream>>>(x, A);
    gemm_kernel<<<(BATCH / 64) * (NEURONS / 64), 256, 0, stream>>>(A, Wt, bias, y);
}